// Round 5
// baseline (402.381 us; speedup 1.0000x reference)
//
#include <hip/hip_runtime.h>
#include <math.h>

// Problem constants (from reference)
#define NH 4
#define HD 64
#define HIDDEN 256
#define BS 32
#define NB 64          // NUM_BLOCKS = MAX_LEN/BS = 2048/32
#define SCALE 0.125f
#define INV_SCALE 8.0f
#define NT 4           // tokens per workgroup

__device__ __forceinline__ float fast_sigmoid(float x) {
    return 1.0f / (1.0f + __expf(-x));
}
__device__ __forceinline__ float readlane_f(float v, int lane) {
    return __int_as_float(__builtin_amdgcn_readlane(__float_as_int(v), lane));
}

// Kernel 1: block means. K means in DOUBLE (selection path must be f64-exact
// vs the np reference to avoid top-k tie flips); V means in float.
// UNCHANGED from R4 (numerics of the selection path must stay bit-identical).
__global__ __launch_bounds__(256) void kcmp_kernel(
    const float* __restrict__ k, const float* __restrict__ v,
    const int* __restrict__ x_offsets,
    double* __restrict__ k_cmpT64, float* __restrict__ v_cmpR) {
    int wg  = blockIdx.x;          // b*NB + blk
    int b   = wg >> 6;
    int blk = wg & 63;
    int tid = threadIdx.x;
    int c4  = tid & 63;            // float4 column (64 per 256-float row)
    int rg  = tid >> 6;            // row group: rows rg*8 .. rg*8+7
    int s0   = x_offsets[b];
    int len  = x_offsets[b + 1] - s0;
    int nblk = len >> 5;
    double skx = 0, sky = 0, skz = 0, skw = 0;
    float4 sv = {0.f, 0.f, 0.f, 0.f};
    if (blk < nblk) {
        const float4* kp = (const float4*)(k + (size_t)(s0 + blk * BS + rg * 8) * HIDDEN) + c4;
        const float4* vp = (const float4*)(v + (size_t)(s0 + blk * BS + rg * 8) * HIDDEN) + c4;
        #pragma unroll
        for (int i = 0; i < 8; ++i) {
            float4 a = kp[i * 64];
            float4 c = vp[i * 64];
            skx += (double)a.x; sky += (double)a.y;
            skz += (double)a.z; skw += (double)a.w;
            sv.x += c.x; sv.y += c.y; sv.z += c.z; sv.w += c.w;
        }
    }
    __shared__ double lk[4][64][4];
    __shared__ float4 lv[4][64];
    lk[rg][c4][0] = skx; lk[rg][c4][1] = sky;
    lk[rg][c4][2] = skz; lk[rg][c4][3] = skw;
    lv[rg][c4] = sv;
    __syncthreads();
    if (rg == 0) {
        double rk[4];
        #pragma unroll
        for (int j = 0; j < 4; ++j)
            rk[j] = (lk[0][c4][j] + lk[1][c4][j] + lk[2][c4][j] + lk[3][c4][j]) * (1.0 / BS);
        float4 b0 = lv[0][c4], b1 = lv[1][c4], b2 = lv[2][c4], b3 = lv[3][c4];
        float4 rv;
        rv.x = (b0.x + b1.x + b2.x + b3.x) * (1.0f / BS);
        rv.y = (b0.y + b1.y + b2.y + b3.y) * (1.0f / BS);
        rv.z = (b0.z + b1.z + b2.z + b3.z) * (1.0f / BS);
        rv.w = (b0.w + b1.w + b2.w + b3.w) * (1.0f / BS);
        int h  = c4 >> 4;
        int d0 = (c4 & 15) * 4;
        double* kt = k_cmpT64 + ((size_t)(b * NH + h) * HD) * NB + blk;
        #pragma unroll
        for (int j = 0; j < 4; ++j) kt[(size_t)(d0 + j) * NB] = rk[j];
        *(float4*)(v_cmpR + ((size_t)(b * NH + h) * NB + blk) * HD + d0) = rv;
    }
}

// Kernel 2: one workgroup = NT=4 consecutive tokens; wave h = head h for all 4.
// 4 independent latency chains interleaved per wave; k_cmpT/v_cmpR loads shared
// across tokens when they're in the same sequence (the common case).
__global__ __launch_bounds__(256) void hstu_main_kernel(
    const float* __restrict__ q, const float* __restrict__ k,
    const float* __restrict__ v, const float* __restrict__ u,
    const float* __restrict__ Wg_cmp,
    const int* __restrict__ x_offsets, const int* __restrict__ batch_ids,
    const int* __restrict__ pos_ids,
    const double* __restrict__ k_cmpT64, const float* __restrict__ v_cmpR,
    float* __restrict__ out, int T) {
    int t0  = blockIdx.x * NT;
    int tid = threadIdx.x;
    int h = __builtin_amdgcn_readfirstlane(tid >> 6);  // wave-uniform -> SGPR
    int d = tid & 63;

    int tj[NT], bj[NT], posj[NT], s0j[NT], qbj[NT];
    #pragma unroll
    for (int j = 0; j < NT; ++j) {
        int t = t0 + j; if (t > T - 1) t = T - 1;   // clamp (T%NT==0 normally)
        tj[j] = t;
        bj[j]   = batch_ids[t];
        posj[j] = pos_ids[t];
        s0j[j]  = x_offsets[bj[j]];
        qbj[j]  = posj[j] >> 5;
    }
    bool same_b = (bj[0] == bj[NT - 1]);   // batch_ids monotone -> all equal

    const float* qr[NT];
    float qv[NT];
    #pragma unroll
    for (int j = 0; j < NT; ++j) {
        qr[j] = q + (size_t)tj[j] * HIDDEN + h * HD;   // uniform base -> s_load
        qv[j] = qr[j][d];
    }

    // g = sigmoid(q[h] . Wg_cmp[h])  (4 interleaved wave reductions)
    float g[NT];
    {
        float w = Wg_cmp[h * HD + d];
        float gs[NT];
        #pragma unroll
        for (int j = 0; j < NT; ++j) gs[j] = qv[j] * w;
        #pragma unroll
        for (int off = 32; off; off >>= 1) {
            #pragma unroll
            for (int j = 0; j < NT; ++j) gs[j] += __shfl_xor(gs[j], off, 64);
        }
        #pragma unroll
        for (int j = 0; j < NT; ++j) g[j] = fast_sigmoid(gs[j]);
    }

    // ---- Compressed scores in f64 (lane = block m = d); k_cmp shared over j ----
    double raw[NT] = {0.0, 0.0, 0.0, 0.0};
    if (same_b) {
        const double* kc = k_cmpT64 + (size_t)(bj[0] * NH + h) * HD * NB + d;
        #pragma unroll 8
        for (int dd = 0; dd < HD; ++dd) {
            double kvv = kc[dd * NB];
            #pragma unroll
            for (int j = 0; j < NT; ++j) raw[j] += (double)qr[j][dd] * kvv;
        }
    } else {
        #pragma unroll
        for (int j = 0; j < NT; ++j) {
            const double* kc = k_cmpT64 + (size_t)(bj[j] * NH + h) * HD * NB + d;
            #pragma unroll 8
            for (int dd = 0; dd < HD; ++dd)
                raw[j] += (double)qr[j][dd] * kc[dd * NB];
        }
    }

    float p[NT];
    unsigned long long key[NT];
    #pragma unroll
    for (int j = 0; j < NT; ++j) {
        double r = raw[j] * 0.125;
        double p64 = 0.0;
        if (d <= qbj[j]) p64 = r / (1.0 + exp(-r)) * 8.0;   // silu*INV_SCALE, f64
        double sel = (d == qbj[j]) ? 1.0 : p64;
        long long sb = __double_as_longlong(sel);
        unsigned long long mk = (unsigned long long)sb;
        key[j] = (sb < 0) ? ~mk : (mk | 0x8000000000000000ull);
        p[j] = (float)p64;
    }

    // ---- top-3 per token (value desc, index asc); need ranks 0 and 2 ----
    int idx0[NT], idx2[NT];
    #pragma unroll
    for (int s = 0; s < 3; ++s) {
        unsigned long long bk[NT]; int ii[NT];
        #pragma unroll
        for (int j = 0; j < NT; ++j) { bk[j] = key[j]; ii[j] = d; }
        #pragma unroll
        for (int off = 32; off; off >>= 1) {
            #pragma unroll
            for (int j = 0; j < NT; ++j) {
                unsigned long long ok = __shfl_xor(bk[j], off, 64);
                int oi = __shfl_xor(ii[j], off, 64);
                if (ok > bk[j] || (ok == bk[j] && oi < ii[j])) { bk[j] = ok; ii[j] = oi; }
            }
        }
        #pragma unroll
        for (int j = 0; j < NT; ++j) {
            if (s == 0) idx0[j] = ii[j];
            if (s == 2) idx2[j] = ii[j];
            if (d == ii[j]) key[j] = 0ull;   // remove winner
        }
    }
    #pragma unroll
    for (int j = 0; j < NT; ++j) {
        idx0[j] = __builtin_amdgcn_readfirstlane(idx0[j]);
        idx2[j] = __builtin_amdgcn_readfirstlane(idx2[j]);
    }

    // ---- o_cmp: sum_m p_m * v_cmp[m][d]; v_cmp shared over j when same_b ----
    // p[j] is 0 for lanes > qbj[j], so readlane needs no masking.
    float oc[NT] = {0.f, 0.f, 0.f, 0.f};
    if (same_b) {
        const float* vc = v_cmpR + (size_t)(bj[0] * NH + h) * NB * HD + d;
        int mmax = qbj[NT - 1];            // pos monotone within a sequence
        for (int mm = 0; mm <= mmax; ++mm) {
            float vv = vc[mm * HD];
            #pragma unroll
            for (int j = 0; j < NT; ++j) oc[j] += readlane_f(p[j], mm) * vv;
        }
    } else {
        #pragma unroll
        for (int j = 0; j < NT; ++j) {
            const float* vc = v_cmpR + (size_t)(bj[j] * NH + h) * NB * HD + d;
            for (int mm = 0; mm <= qbj[j]; ++mm)
                oc[j] += readlane_f(p[j], mm) * vc[mm * HD];
        }
    }
    #pragma unroll
    for (int j = 0; j < NT; ++j) oc[j] *= g[j];

    // ---- o_slc scores: lane = (sel_blk s, pos i); 4 gathers interleaved ----
    int s_sel = d >> 5;
    int i_sel = d & 31;
    float pl[NT];
    #pragma unroll
    for (int j = 0; j < NT; ++j) {
        int blk_l = s_sel ? idx2[j] : idx0[j];
        int pis   = blk_l * BS + i_sel;
        int tgt   = s0j[j] + pis;
        if (tgt > T - 1) tgt = T - 1;
        const float4* kr = (const float4*)(k + (size_t)tgt * HIDDEN + h * HD);
        float sc = 0.f;
        #pragma unroll
        for (int jj = 0; jj < 16; ++jj) {
            float4 kk = kr[jj];
            sc += qr[j][4*jj+0] * kk.x + qr[j][4*jj+1] * kk.y
                + qr[j][4*jj+2] * kk.z + qr[j][4*jj+3] * kk.w;
        }
        sc *= SCALE;
        pl[j] = (pis <= posj[j]) ? sc * fast_sigmoid(sc) * (INV_SCALE * 2.0f) : 0.f;
    }

    // ---- o_slc accumulate: uniform bounds, coalesced V rows, readlane bcast ----
    float os[NT] = {0.f, 0.f, 0.f, 0.f};
    #pragma unroll
    for (int j = 0; j < NT; ++j) {
        #pragma unroll
        for (int s = 0; s < 2; ++s) {
            int blkb = s ? idx2[j] : idx0[j];
            int nval = posj[j] - blkb * BS + 1;
            if (nval > BS) nval = BS;
            if (nval <= 0) continue;               // uniform branch
            const float* vrow = v + (size_t)(s0j[j] + blkb * BS) * HIDDEN + h * HD + d;
            for (int i = 0; i < nval; ++i)
                os[j] += readlane_f(pl[j], s * 32 + i) * vrow[i * HIDDEN];
        }
    }

    // ---- dual LayerNorm over 256 dims + gate by u, sum ----
    __shared__ float red[NT][NH][4];
    {
        float a0[NT], a1[NT], a2[NT], a3[NT];
        #pragma unroll
        for (int j = 0; j < NT; ++j) {
            a0[j] = oc[j]; a1[j] = oc[j] * oc[j];
            a2[j] = os[j]; a3[j] = os[j] * os[j];
        }
        #pragma unroll
        for (int off = 32; off; off >>= 1) {
            #pragma unroll
            for (int j = 0; j < NT; ++j) {
                a0[j] += __shfl_xor(a0[j], off, 64);
                a1[j] += __shfl_xor(a1[j], off, 64);
                a2[j] += __shfl_xor(a2[j], off, 64);
                a3[j] += __shfl_xor(a3[j], off, 64);
            }
        }
        if (d == 0) {
            #pragma unroll
            for (int j = 0; j < NT; ++j) {
                red[j][h][0] = a0[j]; red[j][h][1] = a1[j];
                red[j][h][2] = a2[j]; red[j][h][3] = a3[j];
            }
        }
    }
    __syncthreads();
    #pragma unroll
    for (int j = 0; j < NT; ++j) {
        float tc = 0.f, tc2 = 0.f, ts = 0.f, ts2 = 0.f;
        #pragma unroll
        for (int wv = 0; wv < NH; ++wv) {
            tc += red[j][wv][0]; tc2 += red[j][wv][1];
            ts += red[j][wv][2]; ts2 += red[j][wv][3];
        }
        float muc  = tc  * (1.0f / HIDDEN);
        float varc = tc2 * (1.0f / HIDDEN) - muc * muc;
        float mus  = ts  * (1.0f / HIDDEN);
        float vars = ts2 * (1.0f / HIDDEN) - mus * mus;
        float uval = u[(size_t)tj[j] * HIDDEN + tid];
        float outv = (oc[j] - muc) * rsqrtf(varc + 1e-6f) * uval
                   + (os[j] - mus) * rsqrtf(vars + 1e-6f) * uval;
        if (t0 + j < T) out[(size_t)tj[j] * HIDDEN + tid] = outv;
    }
}

extern "C" void kernel_launch(void* const* d_in, const int* in_sizes, int n_in,
                              void* d_out, int out_size, void* d_ws, size_t ws_size,
                              hipStream_t stream) {
    const float* q      = (const float*)d_in[0];
    const float* k      = (const float*)d_in[1];
    const float* v      = (const float*)d_in[2];
    const float* u      = (const float*)d_in[3];
    const float* Wg_cmp = (const float*)d_in[4];
    // d_in[5] = Wg_slc: dead code in the reference (computed, never used)
    const int* x_offsets = (const int*)d_in[6];
    const int* batch_ids = (const int*)d_in[7];
    const int* pos_ids   = (const int*)d_in[8];

    int T = in_sizes[0] / HIDDEN;
    int B = in_sizes[6] - 1;

    double* k_cmpT64 = (double*)d_ws;                        // B*NH*HD*NB doubles (1 MB)
    float*  v_cmpR   = (float*)(k_cmpT64 + (size_t)B * NH * HD * NB);  // B*NH*NB*HD floats

    kcmp_kernel<<<B * NB, 256, 0, stream>>>(k, v, x_offsets, k_cmpT64, v_cmpR);
    hstu_main_kernel<<<(T + NT - 1) / NT, 256, 0, stream>>>(
        q, k, v, u, Wg_cmp, x_offsets, batch_ids, pos_ids,
        k_cmpT64, v_cmpR, (float*)d_out, T);
}

// Round 6
// 303.582 us; speedup vs baseline: 1.3254x; 1.3254x over previous
//
#include <hip/hip_runtime.h>
#include <math.h>

// Problem constants (from reference)
#define NH 4
#define HD 64
#define HIDDEN 256
#define BS 32
#define NB 64          // NUM_BLOCKS = MAX_LEN/BS = 2048/32
#define SCALE 0.125f
#define INV_SCALE 8.0f

__device__ __forceinline__ float fast_sigmoid(float x) {
    return 1.0f / (1.0f + __expf(-x));
}
__device__ __forceinline__ float readlane_f(float v, int lane) {
    return __int_as_float(__builtin_amdgcn_readlane(__float_as_int(v), lane));
}

// Kernel 1: block means. One thread per column, 32 fully-unrolled coalesced
// row loads (all in flight), no LDS. gridDim.y: 0 = K (f64 means, selection
// path must stay f64-exact vs the np reference), 1 = V (f32 means).
// k_cmpT64 layout: [b][h][d][m] (coalesced over m for the score phase)
// v_cmpR   layout: [b][h][m][d] (coalesced over d for the o_cmp phase)
__global__ __launch_bounds__(256) void kcmp_kernel(
    const float* __restrict__ k, const float* __restrict__ v,
    const int* __restrict__ x_offsets,
    double* __restrict__ k_cmpT64, float* __restrict__ v_cmpR) {
    int bb  = blockIdx.x;          // b*NB + blk
    int b   = bb >> 6;
    int blk = bb & 63;
    int tid = threadIdx.x;         // column: h = tid>>6, d = tid&63
    int s0   = x_offsets[b];
    int len  = x_offsets[b + 1] - s0;
    int nblk = len >> 5;
    int h = tid >> 6, d = tid & 63;
    if (blockIdx.y == 0) {
        double acc = 0.0;
        if (blk < nblk) {
            const float* kp = k + (size_t)(s0 + blk * BS) * HIDDEN + tid;
            #pragma unroll
            for (int i = 0; i < BS; ++i) acc += (double)kp[i * HIDDEN];
            acc *= (1.0 / BS);
        }
        k_cmpT64[((size_t)(b * NH + h) * HD + d) * NB + blk] = acc;
    } else {
        float acc = 0.f;
        if (blk < nblk) {
            const float* vp = v + (size_t)(s0 + blk * BS) * HIDDEN + tid;
            #pragma unroll
            for (int i = 0; i < BS; ++i) acc += vp[i * HIDDEN];
            acc *= (1.0f / BS);
        }
        v_cmpR[((size_t)(b * NH + h) * NB + blk) * HD + d] = acc;
    }
}

// Kernel 2: one workgroup (256 threads = 4 waves) per token t (R4 structure).
// All accumulation loops restructured for deep load pipelining: padded/fixed
// bounds + aggressive unroll, zero-masked tails instead of dynamic trip counts.
__global__ __launch_bounds__(256) void hstu_main_kernel(
    const float* __restrict__ q, const float* __restrict__ k,
    const float* __restrict__ v, const float* __restrict__ u,
    const float* __restrict__ Wg_cmp,
    const int* __restrict__ x_offsets, const int* __restrict__ batch_ids,
    const int* __restrict__ pos_ids,
    const double* __restrict__ k_cmpT64, const float* __restrict__ v_cmpR,
    float* __restrict__ out, int T) {
    int t   = blockIdx.x;
    int tid = threadIdx.x;
    int h = __builtin_amdgcn_readfirstlane(tid >> 6);  // wave-uniform -> SGPR
    int d = tid & 63;
    int b    = batch_ids[t];      // t uniform -> scalar loads
    int pos  = pos_ids[t];
    int s0   = x_offsets[b];
    int qblk = pos >> 5;

    const float* qrow = q + (size_t)t * HIDDEN + h * HD;  // uniform base -> s_load
    float qv = qrow[d];

    // g = sigmoid(q[h] . Wg_cmp[h])  (wave reduction)
    float gsum = qv * Wg_cmp[h * HD + d];
    #pragma unroll
    for (int off = 32; off; off >>= 1) gsum += __shfl_xor(gsum, off, 64);
    float g = fast_sigmoid(gsum);

    // ---- Compressed scores in f64 (selection must be tie-exact vs np ref) ----
    // Fixed 64 iters, unroll 16 -> 16 independent f64 loads in flight.
    const double* kcT = k_cmpT64 + (size_t)(b * NH + h) * HD * NB + d;   // [dd][m=d]
    double raw = 0.0;
    #pragma unroll 16
    for (int dd = 0; dd < HD; ++dd) {
        raw += (double)qrow[dd] * kcT[dd * NB];
    }
    raw *= 0.125;
    double p64 = 0.0;
    if (d <= qblk) p64 = raw / (1.0 + exp(-raw)) * 8.0;   // silu(raw)*INV_SCALE
    double sel = (d == qblk) ? 1.0 : p64;

    // ---- top-3 (need ranks 0 and 2 after topk[1::2]=topk[0::2] dedup) ----
    // Order: value desc, index asc (jax.lax.top_k). (key,idx) pair reduction.
    long long sbits = __double_as_longlong(sel);
    unsigned long long mykey = (unsigned long long)sbits;
    mykey = (sbits < 0) ? ~mykey : (mykey | 0x8000000000000000ull);
    int idx0 = 0, idx2 = 0;
    #pragma unroll
    for (int s = 0; s < 3; ++s) {
        unsigned long long bk = mykey;
        int bi = d;
        #pragma unroll
        for (int off = 32; off; off >>= 1) {
            unsigned long long ok = __shfl_xor(bk, off, 64);
            int oi = __shfl_xor(bi, off, 64);
            if (ok > bk || (ok == bk && oi < bi)) { bk = ok; bi = oi; }
        }
        if (s == 0) idx0 = bi;
        if (s == 2) idx2 = bi;
        if (d == bi) mykey = 0ull;   // remove winner (0 < any finite key)
    }
    idx0 = __builtin_amdgcn_readfirstlane(idx0);   // uniform -> scalar
    idx2 = __builtin_amdgcn_readfirstlane(idx2);

    float p = (float)p64;   // exactly 0 for lanes > qblk

    // ---- o_cmp: sum_m p_m * v_cmp[m][d]. Bound padded to multiple of 16;
    // p broadcasts are 0 for m > qblk, vcR rows 0..63 are all initialized. ----
    const float* vcR = v_cmpR + (size_t)(b * NH + h) * NB * HD + d;   // [m][d]
    float oc = 0.f;
    int mpad = (qblk + 16) & ~15;                  // 16,32,48,64
    #pragma unroll 16
    for (int mm = 0; mm < mpad; ++mm) {
        oc += readlane_f(p, mm) * vcR[mm * HD];
    }
    oc *= g;

    // ---- o_slc scores: lane l = (sel_blk s, pos i); stream own K row ----
    int s_sel = d >> 5;
    int i_sel = d & 31;
    int blk_l = s_sel ? idx2 : idx0;
    int pis   = blk_l * BS + i_sel;
    int tgt   = s0 + pis;
    if (tgt > T - 1) tgt = T - 1;
    const float4* krow = (const float4*)(k + (size_t)tgt * HIDDEN + h * HD);
    float sc = 0.f;
    #pragma unroll
    for (int j = 0; j < 16; ++j) {
        float4 kk = krow[j];
        sc += qrow[4*j+0] * kk.x + qrow[4*j+1] * kk.y
            + qrow[4*j+2] * kk.z + qrow[4*j+3] * kk.w;
    }
    sc *= SCALE;
    float pl = (pis <= pos) ? sc * fast_sigmoid(sc) * (INV_SCALE * 2.0f) : 0.f;

    // ---- o_slc accumulate: fixed 2x32 fully-unrolled (64 loads in flight).
    // pl broadcasts are 0 beyond pos / for invalid blocks; idx2>qblk would read
    // out of the sequence, so substitute block 0 (its pl values are all 0). ----
    float os = 0.f;
    int bsafe0 = idx0;                             // idx0 <= qblk always
    int bsafe1 = (idx2 > qblk) ? 0 : idx2;
    const float* vr0 = v + (size_t)(s0 + bsafe0 * BS) * HIDDEN + h * HD + d;
    const float* vr1 = v + (size_t)(s0 + bsafe1 * BS) * HIDDEN + h * HD + d;
    #pragma unroll
    for (int i = 0; i < BS; ++i) {
        os += readlane_f(pl, i) * vr0[i * HIDDEN];
        os += readlane_f(pl, 32 + i) * vr1[i * HIDDEN];
    }

    // ---- dual LayerNorm over 256 dims + gate by u, sum ----
    __shared__ float red[NH][4];
    float sc_ = oc, sc2 = oc * oc, ss_ = os, ss2 = os * os;
    #pragma unroll
    for (int off = 32; off; off >>= 1) {
        sc_ += __shfl_xor(sc_, off, 64);
        sc2 += __shfl_xor(sc2, off, 64);
        ss_ += __shfl_xor(ss_, off, 64);
        ss2 += __shfl_xor(ss2, off, 64);
    }
    if (d == 0) { red[h][0] = sc_; red[h][1] = sc2; red[h][2] = ss_; red[h][3] = ss2; }
    __syncthreads();
    float tc = 0.f, tc2 = 0.f, ts = 0.f, ts2 = 0.f;
    #pragma unroll
    for (int w = 0; w < NH; ++w) {
        tc += red[w][0]; tc2 += red[w][1]; ts += red[w][2]; ts2 += red[w][3];
    }
    float muc  = tc  * (1.0f / HIDDEN);
    float varc = tc2 * (1.0f / HIDDEN) - muc * muc;
    float mus  = ts  * (1.0f / HIDDEN);
    float vars = ts2 * (1.0f / HIDDEN) - mus * mus;
    float uval = u[(size_t)t * HIDDEN + tid];
    float outv = (oc - muc) * rsqrtf(varc + 1e-6f) * uval
               + (os - mus) * rsqrtf(vars + 1e-6f) * uval;
    out[(size_t)t * HIDDEN + tid] = outv;
}

extern "C" void kernel_launch(void* const* d_in, const int* in_sizes, int n_in,
                              void* d_out, int out_size, void* d_ws, size_t ws_size,
                              hipStream_t stream) {
    const float* q      = (const float*)d_in[0];
    const float* k      = (const float*)d_in[1];
    const float* v      = (const float*)d_in[2];
    const float* u      = (const float*)d_in[3];
    const float* Wg_cmp = (const float*)d_in[4];
    // d_in[5] = Wg_slc: dead code in the reference (computed, never used)
    const int* x_offsets = (const int*)d_in[6];
    const int* batch_ids = (const int*)d_in[7];
    const int* pos_ids   = (const int*)d_in[8];

    int T = in_sizes[0] / HIDDEN;
    int B = in_sizes[6] - 1;

    double* k_cmpT64 = (double*)d_ws;                        // B*NH*HD*NB doubles (1 MB)
    float*  v_cmpR   = (float*)(k_cmpT64 + (size_t)B * NH * HD * NB);  // B*NH*NB*HD floats

    kcmp_kernel<<<dim3(B * NB, 2), 256, 0, stream>>>(k, v, x_offsets, k_cmpT64, v_cmpR);
    hstu_main_kernel<<<T, 256, 0, stream>>>(q, k, v, u, Wg_cmp,
                                            x_offsets, batch_ids, pos_ids,
                                            k_cmpT64, v_cmpR, (float*)d_out, T);
}

// Round 7
// 265.291 us; speedup vs baseline: 1.5167x; 1.1443x over previous
//
#include <hip/hip_runtime.h>
#include <math.h>

// Problem constants (from reference)
#define NH 4
#define HD 64
#define HIDDEN 256
#define BS 32
#define NB 64          // NUM_BLOCKS = MAX_LEN/BS = 2048/32
#define SCALE 0.125f
#define INV_SCALE 8.0f

__device__ __forceinline__ float fast_sigmoid(float x) {
    return 1.0f / (1.0f + __expf(-x));
}
__device__ __forceinline__ float readlane_f(float v, int lane) {
    return __int_as_float(__builtin_amdgcn_readlane(__float_as_int(v), lane));
}

// Kernel 1: block means. One thread per column, 32 fully-unrolled coalesced
// row loads. gridDim.y: 0 = K (f64 means, selection path must stay f64-exact
// vs the np reference), 1 = V (f32 means). Paired layouts for the main kernel:
// k_cmp2 (double): [b][h][dd2=dd/2][m][par=dd&1]  -> lane-d double2 load = (2dd2,2dd2+1) at m=d
// v_cmp2 (float) : [b][h][m2=m/2][d][par=m&1]     -> lane-d float2  load = (2m2,2m2+1) at d
__global__ __launch_bounds__(256) void kcmp_kernel(
    const float* __restrict__ k, const float* __restrict__ v,
    const int* __restrict__ x_offsets,
    double* __restrict__ k_cmp2, float* __restrict__ v_cmp2) {
    int bb  = blockIdx.x;          // b*NB + blk
    int b   = bb >> 6;
    int blk = bb & 63;
    int tid = threadIdx.x;         // column: h = tid>>6, d = tid&63
    int s0   = x_offsets[b];
    int len  = x_offsets[b + 1] - s0;
    int nblk = len >> 5;
    int h = tid >> 6, d = tid & 63;
    if (blockIdx.y == 0) {
        double acc = 0.0;
        if (blk < nblk) {
            const float* kp = k + (size_t)(s0 + blk * BS) * HIDDEN + tid;
            #pragma unroll
            for (int i = 0; i < BS; ++i) acc += (double)kp[i * HIDDEN];
            acc *= (1.0 / BS);
        }
        // element (dd=d, m=blk)
        k_cmp2[((size_t)(b * NH + h) * 32 + (d >> 1)) * 128 + blk * 2 + (d & 1)] = acc;
    } else {
        float acc = 0.f;
        if (blk < nblk) {
            const float* vp = v + (size_t)(s0 + blk * BS) * HIDDEN + tid;
            #pragma unroll
            for (int i = 0; i < BS; ++i) acc += vp[i * HIDDEN];
            acc *= (1.0f / BS);
        }
        // element (m=blk, d)
        v_cmp2[((size_t)(b * NH + h) * 32 + (blk >> 1)) * 128 + d * 2 + (blk & 1)] = acc;
    }
}

// Kernel 2: one workgroup (256 threads = 4 waves) per token t.
// Wave h = head h. Lane roles: d (= block m in cmp phase); (c=lane>>4, r=lane&15)
// in the coalesced K-gather phase.
__global__ __launch_bounds__(256) void hstu_main_kernel(
    const float* __restrict__ q, const float* __restrict__ k,
    const float* __restrict__ v, const float* __restrict__ u,
    const float* __restrict__ Wg_cmp,
    const int* __restrict__ x_offsets, const int* __restrict__ batch_ids,
    const int* __restrict__ pos_ids,
    const double* __restrict__ k_cmp2, const float* __restrict__ v_cmp2,
    float* __restrict__ out, int T) {
    int t   = blockIdx.x;
    int tid = threadIdx.x;
    int h = __builtin_amdgcn_readfirstlane(tid >> 6);  // wave-uniform -> SGPR
    int d = tid & 63;
    int b    = batch_ids[t];      // t uniform -> scalar loads
    int pos  = pos_ids[t];
    int s0   = x_offsets[b];
    int qblk = pos >> 5;

    const float* qrow = q + (size_t)t * HIDDEN + h * HD;  // uniform base -> s_load
    float qv = qrow[d];

    // g = sigmoid(q[h] . Wg_cmp[h])  (wave reduction)
    float gsum = qv * Wg_cmp[h * HD + d];
    #pragma unroll
    for (int off = 32; off; off >>= 1) gsum += __shfl_xor(gsum, off, 64);
    float g = fast_sigmoid(gsum);

    // ---- Compressed scores in f64 (selection must be tie-exact vs np ref) ----
    // Paired layout: 32 double2 loads (1 KB/wave-instr, minimal lines).
    const double2* kc2 = (const double2*)k_cmp2 + (size_t)(b * NH + h) * 32 * 64 + d;
    double raw = 0.0;
    #pragma unroll 16
    for (int dd2 = 0; dd2 < 32; ++dd2) {
        double2 kk = kc2[dd2 * 64];
        raw += (double)qrow[2 * dd2] * kk.x + (double)qrow[2 * dd2 + 1] * kk.y;
    }
    raw *= 0.125;
    double p64 = 0.0;
    if (d <= qblk) p64 = raw / (1.0 + exp(-raw)) * 8.0;   // silu(raw)*INV_SCALE
    double sel = (d == qblk) ? 1.0 : p64;

    // ---- top-3 (need ranks 0 and 2 after topk[1::2]=topk[0::2] dedup) ----
    // Monotone u64 key; index packed into low 6 mantissa bits (ambiguity < 2^-46).
    long long sbits = __double_as_longlong(sel);
    unsigned long long mykey = (unsigned long long)sbits;
    mykey = (sbits < 0) ? ~mykey : (mykey | 0x8000000000000000ull);
    mykey = (mykey & ~63ull) | (unsigned long long)(63 - d);
    int idx0 = 0, idx2 = 0;
    #pragma unroll
    for (int s = 0; s < 3; ++s) {
        unsigned long long bk = mykey;
        #pragma unroll
        for (int off = 32; off; off >>= 1) {
            unsigned long long ok = __shfl_xor(bk, off, 64);
            if (ok > bk) bk = ok;
        }
        int im = 63 - (int)(bk & 63ull);
        if (s == 0) idx0 = im;
        if (s == 2) idx2 = im;
        if (d == im) mykey = 0ull;   // remove winner (0 < any finite key)
    }
    idx0 = __builtin_amdgcn_readfirstlane(idx0);   // uniform -> scalar
    idx2 = __builtin_amdgcn_readfirstlane(idx2);

    float p = (float)p64;   // exactly 0 for lanes > qblk

    // ---- o_cmp: sum_m p_m * v_cmp[m][d]; paired over m (32 float2 loads) ----
    const float2* vc2 = (const float2*)v_cmp2 + (size_t)(b * NH + h) * 32 * 64 + d;
    float oc = 0.f;
    int mp2 = ((qblk >> 1) + 8) & ~7;              // 8,16,24,32 pairs; covers qblk
    #pragma unroll 8
    for (int m2 = 0; m2 < mp2; ++m2) {
        float2 vv = vc2[m2 * 64];
        oc += readlane_f(p, 2 * m2) * vv.x + readlane_f(p, 2 * m2 + 1) * vv.y;
    }
    oc *= g;

    // ---- o_slc scores, coalesced: lane=(c,r); 4 its x 16 rows; each instr
    // touches 16 lines (4 lanes share a 64B line of one row). ----
    __shared__ float pls[NH][64];
    int r = d & 15, c = d >> 4;
    // q chunks for this lane's c: floats 16c'+... via 4 broadcast float4 loads
    float4 qf[4];
    {
        const float4* q4 = (const float4*)qrow;
        #pragma unroll
        for (int j = 0; j < 4; ++j) qf[j] = q4[c + 4 * j];
    }
    #pragma unroll
    for (int it = 0; it < 4; ++it) {
        int rowidx = it * 16 + r;
        int ss = rowidx >> 5, ii = rowidx & 31;
        int blk_l = ss ? idx2 : idx0;              // scalar
        int pis   = blk_l * BS + ii;
        int tgt   = s0 + pis;
        if (tgt > T - 1) tgt = T - 1;
        const float4* kr = (const float4*)(k + (size_t)tgt * HIDDEN + h * HD) + c;
        float ps = 0.f;
        #pragma unroll
        for (int j = 0; j < 4; ++j) {
            float4 kk = kr[j * 4];
            ps += qf[j].x * kk.x + qf[j].y * kk.y + qf[j].z * kk.z + qf[j].w * kk.w;
        }
        ps += __shfl_xor(ps, 16, 64);
        ps += __shfl_xor(ps, 32, 64);
        if (c == 0) {
            float scv = ps * SCALE;
            float plv = (pis <= pos) ? scv * fast_sigmoid(scv) * (INV_SCALE * 2.0f) : 0.f;
            pls[h][rowidx] = plv;
        }
    }
    float plreg = pls[h][d];   // wave-private: no barrier needed (lgkmcnt only)

    // ---- o_slc accumulate: fixed 2x32 fully-unrolled, coalesced V rows.
    // plreg broadcasts are 0 beyond pos / for invalid blocks; substitute block 0
    // when idx2 is invalid so addresses stay in-sequence (products are 0). ----
    float os = 0.f;
    int bsafe1 = (idx2 > qblk) ? 0 : idx2;
    const float* vr0 = v + (size_t)(s0 + idx0  * BS) * HIDDEN + h * HD + d;
    const float* vr1 = v + (size_t)(s0 + bsafe1 * BS) * HIDDEN + h * HD + d;
    #pragma unroll
    for (int i = 0; i < BS; ++i) {
        os += readlane_f(plreg, i) * vr0[i * HIDDEN];
        os += readlane_f(plreg, 32 + i) * vr1[i * HIDDEN];
    }

    // ---- dual LayerNorm over 256 dims + gate by u, sum ----
    __shared__ float red[NH][4];
    float sc_ = oc, sc2 = oc * oc, ss_ = os, ss2 = os * os;
    #pragma unroll
    for (int off = 32; off; off >>= 1) {
        sc_ += __shfl_xor(sc_, off, 64);
        sc2 += __shfl_xor(sc2, off, 64);
        ss_ += __shfl_xor(ss_, off, 64);
        ss2 += __shfl_xor(ss2, off, 64);
    }
    if (d == 0) { red[h][0] = sc_; red[h][1] = sc2; red[h][2] = ss_; red[h][3] = ss2; }
    __syncthreads();
    float tc = 0.f, tc2 = 0.f, ts = 0.f, ts2 = 0.f;
    #pragma unroll
    for (int w = 0; w < NH; ++w) {
        tc += red[w][0]; tc2 += red[w][1]; ts += red[w][2]; ts2 += red[w][3];
    }
    float muc  = tc  * (1.0f / HIDDEN);
    float varc = tc2 * (1.0f / HIDDEN) - muc * muc;
    float mus  = ts  * (1.0f / HIDDEN);
    float vars = ts2 * (1.0f / HIDDEN) - mus * mus;
    float uval = u[(size_t)t * HIDDEN + tid];
    float outv = (oc - muc) * rsqrtf(varc + 1e-6f) * uval
               + (os - mus) * rsqrtf(vars + 1e-6f) * uval;
    out[(size_t)t * HIDDEN + tid] = outv;
}

extern "C" void kernel_launch(void* const* d_in, const int* in_sizes, int n_in,
                              void* d_out, int out_size, void* d_ws, size_t ws_size,
                              hipStream_t stream) {
    const float* q      = (const float*)d_in[0];
    const float* k      = (const float*)d_in[1];
    const float* v      = (const float*)d_in[2];
    const float* u      = (const float*)d_in[3];
    const float* Wg_cmp = (const float*)d_in[4];
    // d_in[5] = Wg_slc: dead code in the reference (computed, never used)
    const int* x_offsets = (const int*)d_in[6];
    const int* batch_ids = (const int*)d_in[7];
    const int* pos_ids   = (const int*)d_in[8];

    int T = in_sizes[0] / HIDDEN;
    int B = in_sizes[6] - 1;

    double* k_cmp2 = (double*)d_ws;                       // B*NH*HD*NB doubles (1 MB)
    float*  v_cmp2 = (float*)(k_cmp2 + (size_t)B * NH * HD * NB);  // B*NH*NB*HD floats

    kcmp_kernel<<<dim3(B * NB, 2), 256, 0, stream>>>(k, v, x_offsets, k_cmp2, v_cmp2);
    hstu_main_kernel<<<T, 256, 0, stream>>>(q, k, v, u, Wg_cmp,
                                            x_offsets, batch_ids, pos_ids,
                                            k_cmp2, v_cmp2, (float*)d_out, T);
}